// Round 5
// baseline (296.410 us; speedup 1.0000x reference)
//
#include <hip/hip_runtime.h>
#include <hip/hip_bf16.h>
#include <hip/hip_cooperative_groups.h>

namespace cg = cooperative_groups;

#define CC    32
#define HH    80
#define WW    80
#define HW    6400     // 80*80
#define HPQ   77
#define WPQ   77
#define PP    5929     // 77*77
#define MSTR  81
#define NTILE 93       // 93 candidate blocks of 64
#define QTILES 372     // 5952/16 tiles
#define NBLK  512      // 2 blocks/CU x 256 CU, co-residency via __launch_bounds__(256,2)
#define NEGINF (-1e9f)

typedef __attribute__((ext_vector_type(4))) float f32x4;
typedef __attribute__((ext_vector_type(8))) short bf16x8;
typedef __attribute__((ext_vector_type(8))) unsigned short u16x8;

__device__ __forceinline__ void split_bf16(float v, unsigned short& hi, unsigned short& lo) {
    __hip_bfloat16 h = __float2bfloat16(v);
    float hf = __bfloat162float(h);
    __hip_bfloat16 lw = __float2bfloat16(v - hf);
    hi = *reinterpret_cast<unsigned short*>(&h);
    lo = *reinterpret_cast<unsigned short*>(&lw);
}

// ---- shared device helpers (used by both coop phases and fallback kernels) ----

__device__ __forceinline__ void packB_unit(const float* __restrict__ low,
                                           unsigned short* __restrict__ Bhi,
                                           unsigned short* __restrict__ Blo,
                                           int unit, int tid) {
    int t = unit * 256 + tid;
    int l = t & 63;
    int s = (t >> 6) & 15;
    int u = t >> 10;
    int n = l & 15, quad = l >> 4;
    int p = u * 16 + n;
    int kbase = s * 32 + quad * 8;
    u16x8 vh, vl;
    if (p < PP) {
        int pi = p / WPQ, pj = p % WPQ;
        int base = (kbase >> 4) * HW + pi * WW + pj;   // c fixed across j
#pragma unroll
        for (int j = 0; j < 8; ++j) {
            int kk = kbase + j;
            int di = (kk >> 2) & 3, dj = kk & 3;
            unsigned short h, lo2;
            split_bf16(low[base + di * WW + dj], h, lo2);
            vh[j] = h; vl[j] = lo2;
        }
    } else {
#pragma unroll
        for (int j = 0; j < 8; ++j) { vh[j] = 0; vl[j] = 0; }
    }
    int off = t * 8;
    *reinterpret_cast<u16x8*>(Bhi + off) = vh;
    *reinterpret_cast<u16x8*>(Blo + off) = vl;
}

// flags + compaction + A-pack for patch block g (0..92); uses the caller's LDS
struct FlagsLds { float part[4][64]; int s_n; int s_q[64]; int s_slot[64]; };

__device__ __forceinline__ void flags_block(const float* __restrict__ low,
                                            const float* __restrict__ high,
                                            const int* __restrict__ mask,
                                            float* __restrict__ invn,
                                            int* __restrict__ excl,
                                            int* __restrict__ qslot,
                                            int* __restrict__ nvalid,
                                            unsigned short* __restrict__ Ahi,
                                            unsigned short* __restrict__ Alo,
                                            FlagsLds& L, int g, int tid) {
    const int pl = tid & 63;
    const int slc = tid >> 6;          // channel slice 0..3
    const int p = g * 64 + pl;
    float s = 0.f;
    if (p < PP) {
        int pi = p / WPQ, pj = p % WPQ;
        int base = pi * WW + pj;
        for (int c = slc * 8; c < slc * 8 + 8; ++c) {
            int b2 = c * HW + base;
#pragma unroll
            for (int di = 0; di < 4; ++di)
#pragma unroll
                for (int dj = 0; dj < 4; ++dj) {
                    float v = low[b2 + di * WW + dj];
                    s += v * v;
                }
        }
    }
    L.part[slc][pl] = s;
    if (tid == 0) L.s_n = 0;
    __syncthreads();
    if (tid < 64 && p < PP) {
        float t4 = L.part[0][tid] + L.part[1][tid] + L.part[2][tid] + L.part[3][tid];
        invn[p] = 1.0f / (sqrtf(t4) + 1e-6f);
        int pi = p / WPQ, pj = p % WPQ;
        int m00 = mask[pi * MSTR + pj];
        int m01 = mask[pi * MSTR + pj + 4];
        int m10 = mask[(pi + 4) * MSTR + pj];
        int m11 = mask[(pi + 4) * MSTR + pj + 4];
        excl[p] = (m00 == 1) ? 1 : 0;
        int slot = -1;
        if (m00 != 0 && m01 != 0 && m10 != 0 && m11 != 0) {
            slot = atomicAdd(nvalid, 1);
            int li = atomicAdd(&L.s_n, 1);
            L.s_q[li] = p;
            L.s_slot[li] = slot;
        }
        qslot[p] = slot;
    }
    __syncthreads();
    // A-pack: 4 queries in flight, 64 chunks (=512 elems) each
    const int nn = L.s_n;
    const int c64 = tid & 63;
    const int ss = c64 >> 2, qd = c64 & 3;
    const int kbase = ss * 32 + qd * 8;
    for (int vi = tid >> 6; vi < nn; vi += 4) {
        int q = L.s_q[vi], slot = L.s_slot[vi];
        int qi = q / WPQ, qj = q % WPQ;
        int base = (kbase >> 4) * HW + qi * WW + qj;
        u16x8 vh, vl;
#pragma unroll
        for (int j = 0; j < 8; ++j) {
            int kk = kbase + j;
            int di = (kk >> 2) & 3, dj = kk & 3;
            unsigned short h, lo2;
            split_bf16(high[base + di * WW + dj], h, lo2);
            vh[j] = h; vl[j] = lo2;
        }
        int u = slot >> 4, m = slot & 15;
        int off = u * 8192 + ss * 512 + (qd * 16 + m) * 8;
        *reinterpret_cast<u16x8*>(Ahi + off) = vh;
        *reinterpret_cast<u16x8*>(Alo + off) = vl;
    }
    // slots in [nv, tile-end): garbage score ROWS only; bestpk[slot>=nv] never read.
}

__device__ __forceinline__ void score_pair(const unsigned short* __restrict__ Ahi,
                                           const unsigned short* __restrict__ Alo,
                                           const unsigned short* __restrict__ Bhi,
                                           const unsigned short* __restrict__ Blo,
                                           const int* __restrict__ excl,
                                           const float* __restrict__ invn,
                                           unsigned long long* __restrict__ bestpk,
                                           int pblk, int qblk, int tid) {
    const int w = tid >> 6;
    const int l = tid & 63;
    const int n = l & 15, quad = l >> 4;
    const int qtile = qblk * 4 + w;
    const int bbase = pblk * 4 * 8192 + l * 8;

    int gpv[4]; bool exv[4]; float ivv[4];
#pragma unroll
    for (int pt = 0; pt < 4; ++pt) {
        gpv[pt] = pblk * 64 + pt * 16 + n;
        if (gpv[pt] < PP) { exv[pt] = (excl[gpv[pt]] != 0); ivv[pt] = invn[gpv[pt]]; }
        else              { exv[pt] = true;                 ivv[pt] = 0.f; }
    }

    f32x4 acc[4];
#pragma unroll
    for (int pt = 0; pt < 4; ++pt) acc[pt] = (f32x4){0.f, 0.f, 0.f, 0.f};

    const int abase = qtile * 8192 + l * 8;
#pragma unroll 4
    for (int s = 0; s < 16; ++s) {
        bf16x8 ah = *reinterpret_cast<const bf16x8*>(Ahi + abase + s * 512);
        bf16x8 al = *reinterpret_cast<const bf16x8*>(Alo + abase + s * 512);
#pragma unroll
        for (int pt = 0; pt < 4; ++pt) {
            bf16x8 bh = *reinterpret_cast<const bf16x8*>(Bhi + bbase + pt * 8192 + s * 512);
            bf16x8 bl = *reinterpret_cast<const bf16x8*>(Blo + bbase + pt * 8192 + s * 512);
            acc[pt] = __builtin_amdgcn_mfma_f32_16x16x32_bf16(ah, bh, acc[pt], 0, 0, 0);
            acc[pt] = __builtin_amdgcn_mfma_f32_16x16x32_bf16(ah, bl, acc[pt], 0, 0, 0);
            acc[pt] = __builtin_amdgcn_mfma_f32_16x16x32_bf16(al, bh, acc[pt], 0, 0, 0);
        }
    }

    // C/D: col n = l&15 (candidate), row m = quad*4 + r (query within qtile)
    float bs[4]; int bi[4];
#pragma unroll
    for (int r = 0; r < 4; ++r) { bs[r] = -3.4e38f; bi[r] = 0x7fffffff; }
#pragma unroll
    for (int pt = 0; pt < 4; ++pt) {
        if (gpv[pt] < PP) {
#pragma unroll
            for (int r = 0; r < 4; ++r) {
                float sv = exv[pt] ? NEGINF : acc[pt][r] * ivv[pt];
                if (sv > bs[r]) { bs[r] = sv; bi[r] = gpv[pt]; }  // pt asc -> lowest gp on tie
            }
        }
    }
#pragma unroll
    for (int off = 1; off <= 8; off <<= 1) {
#pragma unroll
        for (int r = 0; r < 4; ++r) {
            float s2 = __shfl_xor(bs[r], off, 64);
            int   i2 = __shfl_xor(bi[r], off, 64);
            if (s2 > bs[r] || (s2 == bs[r] && i2 < bi[r])) { bs[r] = s2; bi[r] = i2; }
        }
    }
    if (n == 0) {
#pragma unroll
        for (int r = 0; r < 4; ++r) {
            if (bi[r] != 0x7fffffff) {
                unsigned ub = __float_as_uint(bs[r]);
                unsigned mo = (ub & 0x80000000u) ? ~ub : (ub | 0x80000000u);
                unsigned long long pk = ((unsigned long long)mo << 32) | (unsigned)(~bi[r]);
                int slot = qtile * 16 + quad * 4 + r;
                atomicMax(bestpk + slot, pk);
            }
        }
    }
}

struct OutLds { int scnt[64]; int soff[64][17]; };

__device__ __forceinline__ void out_block(const float* __restrict__ low,
                                          const int* __restrict__ qslot,
                                          const unsigned long long* __restrict__ bestpk,
                                          float* __restrict__ out,
                                          OutLds& L, int blk, int tid) {
    const int pixb = blk * 64;
    if (tid < 64) {
        int pix = pixb + tid;
        int i = pix / WW, j = pix % WW;
        int nn = 0;
#pragma unroll
        for (int di = 0; di < 4; ++di) {
            int qi = i - di;
            if (qi < 0 || qi >= HPQ) continue;
#pragma unroll
            for (int dj = 0; dj < 4; ++dj) {
                int qj = j - dj;
                if (qj < 0 || qj >= WPQ) continue;
                int sl = qslot[qi * WPQ + qj];
                if (sl >= 0) {
                    int bb = (int)(~(unsigned)bestpk[sl]);   // low 32 bits = ~best_idx
                    L.soff[tid][nn++] = (bb / WPQ + di) * WW + (bb % WPQ + dj);
                }
            }
        }
        L.scnt[tid] = nn;
    }
    __syncthreads();
    const int pl = tid & 63, cg2 = tid >> 6;
    const int nn = L.scnt[pl];
    const int pix = pixb + pl;
    const float inv = 1.0f / ((float)nn + 1e-6f);
#pragma unroll
    for (int k = 0; k < 8; ++k) {
        int c = cg2 * 8 + k;
        int base = c * HW;
        float a;
        if (nn > 0) {
            a = 0.f;
            for (int t2 = 0; t2 < nn; ++t2) a += low[base + L.soff[pl][t2]];
            a *= inv;
        } else {
            a = low[base + pix];
        }
        out[base + pix] = a;
    }
}

// ================= cooperative mega-kernel =================
__global__ __launch_bounds__(256, 2) void k_all(const float* __restrict__ low,
                                                const float* __restrict__ high,
                                                const int* __restrict__ mask,
                                                float* __restrict__ invn,
                                                int* __restrict__ excl,
                                                int* __restrict__ qslot,
                                                int* __restrict__ nvalid,
                                                unsigned short* __restrict__ Bhi,
                                                unsigned short* __restrict__ Blo,
                                                unsigned short* __restrict__ Ahi,
                                                unsigned short* __restrict__ Alo,
                                                unsigned long long* __restrict__ bestpk,
                                                float* __restrict__ out) {
    cg::grid_group grid = cg::this_grid();
    const int b = blockIdx.x;
    const int tid = threadIdx.x;
    __shared__ union { FlagsLds f; OutLds o; } lds;

    // phase 0: zero flags + B-pack
    {
        int gt = b * 256 + tid;
        if (gt < 6144) bestpk[gt] = 0ull;
        if (gt == 6144) *nvalid = 0;
        for (int unit = b; unit < QTILES * 4; unit += NBLK)
            packB_unit(low, Bhi, Blo, unit, tid);
    }
    grid.sync();

    // phase 1: flags + compaction + A-pack
    if (b < NTILE)
        flags_block(low, high, mask, invn, excl, qslot, nvalid, Ahi, Alo, lds.f, b, tid);
    grid.sync();

    // phase 2: score
    {
        const int nv = *nvalid;
        const int nqblk = (nv + 63) >> 6;
        const int npairs = NTILE * nqblk;       // nv~371 -> 558 pairs
        for (int pair = b; pair < npairs; pair += NBLK)
            score_pair(Ahi, Alo, Bhi, Blo, excl, invn, bestpk,
                       pair % NTILE, pair / NTILE, tid);
    }
    grid.sync();

    // phase 3: gather + overlap-add + normalize
    if (b < 100)
        out_block(low, qslot, bestpk, out, lds.o, b, tid);
}

// ================= fallback multi-kernel chain (R3, known-good) =================
__global__ __launch_bounds__(256) void k_main(const float* __restrict__ low,
                                              const float* __restrict__ high,
                                              const int* __restrict__ mask,
                                              float* __restrict__ invn,
                                              int* __restrict__ excl,
                                              int* __restrict__ qslot,
                                              int* __restrict__ nvalid,
                                              unsigned short* __restrict__ Bhi,
                                              unsigned short* __restrict__ Blo,
                                              unsigned short* __restrict__ Ahi,
                                              unsigned short* __restrict__ Alo) {
    const int g = blockIdx.x;
    if (g >= NTILE) {
        packB_unit(low, Bhi, Blo, g - NTILE, threadIdx.x);
        return;
    }
    __shared__ FlagsLds L;
    flags_block(low, high, mask, invn, excl, qslot, nvalid, Ahi, Alo, L, g, threadIdx.x);
}

__global__ __launch_bounds__(256) void k_score(const unsigned short* __restrict__ Ahi,
                                               const unsigned short* __restrict__ Alo,
                                               const unsigned short* __restrict__ Bhi,
                                               const unsigned short* __restrict__ Blo,
                                               const int* __restrict__ excl,
                                               const float* __restrict__ invn,
                                               const int* __restrict__ nvalid,
                                               unsigned long long* __restrict__ bestpk) {
    const int nv = *nvalid;
    for (int qblk = blockIdx.y; qblk * 64 < nv; qblk += 12)
        score_pair(Ahi, Alo, Bhi, Blo, excl, invn, bestpk, blockIdx.x, qblk, threadIdx.x);
}

__global__ __launch_bounds__(256) void k_out(const float* __restrict__ low,
                                             const int* __restrict__ qslot,
                                             const unsigned long long* __restrict__ bestpk,
                                             float* __restrict__ out) {
    __shared__ OutLds L;
    out_block(low, qslot, bestpk, out, L, blockIdx.x, threadIdx.x);
}

extern "C" void kernel_launch(void* const* d_in, const int* in_sizes, int n_in,
                              void* d_out, int out_size, void* d_ws, size_t ws_size,
                              hipStream_t stream) {
    const float* low  = (const float*)d_in[0];
    const float* high = (const float*)d_in[1];
    const int*   mask = (const int*)d_in[2];
    float* out = (float*)d_out;

    char* ws = (char*)d_ws;
    int* nvalid = (int*)ws;                                       // 64 B
    unsigned long long* bestpk = (unsigned long long*)(ws + 64);  // 6144*8 = 49152 -> 49216
    int*   qslot = (int*)(ws + 49216);                            // 23808 -> 73024
    float* invn  = (float*)(ws + 73024);                          // 23808 -> 96832
    int*   excl  = (int*)(ws + 96832);                            // 23808 -> 120640
    unsigned short* Ahi = (unsigned short*)(ws + 120640);         // 372 tiles: 6,094,848
    unsigned short* Alo = (unsigned short*)(ws + 6215488);        // 6,094,848
    unsigned short* Bhi = (unsigned short*)(ws + 12310336);       // 6,094,848
    unsigned short* Blo = (unsigned short*)(ws + 18405184);       // end 24,500,032 (~24.5 MB)

    void* args[] = {(void*)&low, (void*)&high, (void*)&mask, (void*)&invn, (void*)&excl,
                    (void*)&qslot, (void*)&nvalid, (void*)&Bhi, (void*)&Blo,
                    (void*)&Ahi, (void*)&Alo, (void*)&bestpk, (void*)&out};
    hipError_t rc = hipLaunchCooperativeKernel((const void*)k_all, dim3(NBLK), dim3(256),
                                               args, 0, stream);
    if (rc != hipSuccess) {
        // fallback: proven 3-kernel chain
        hipMemsetAsync(ws, 0, 49216, stream);   // nvalid + bestpk
        hipLaunchKernelGGL(k_main, dim3(NTILE + QTILES * 4), dim3(256), 0, stream,
                           low, high, mask, invn, excl, qslot, nvalid, Bhi, Blo, Ahi, Alo);
        hipLaunchKernelGGL(k_score, dim3(NTILE, 12), dim3(256), 0, stream,
                           Ahi, Alo, Bhi, Blo, excl, invn, nvalid, bestpk);
        hipLaunchKernelGGL(k_out, dim3(100), dim3(256), 0, stream,
                           low, qslot, bestpk, out);
    }
}

// Round 6
// 114.763 us; speedup vs baseline: 2.5828x; 2.5828x over previous
//
#include <hip/hip_runtime.h>
#include <hip/hip_bf16.h>

#define CC    32
#define HH    80
#define WW    80
#define HW    6400     // 80*80
#define HPQ   77
#define WPQ   77
#define PP    5929     // 77*77
#define MSTR  81
#define NTILE 93       // 93 candidate blocks of 64
#define QTILES 372     // 5952/16 tiles
#define NEGINF (-1e9f)

typedef __attribute__((ext_vector_type(4))) float f32x4;
typedef __attribute__((ext_vector_type(8))) short bf16x8;
typedef __attribute__((ext_vector_type(8))) unsigned short u16x8;

__device__ __forceinline__ void split_bf16(float v, unsigned short& hi, unsigned short& lo) {
    __hip_bfloat16 h = __float2bfloat16(v);
    float hf = __bfloat162float(h);
    __hip_bfloat16 lw = __float2bfloat16(v - hf);
    hi = *reinterpret_cast<unsigned short*>(&h);
    lo = *reinterpret_cast<unsigned short*>(&lw);
}

// ---- device helpers (byte-identical math to the R3 chain that passed absmax 0.0) ----

__device__ __forceinline__ void packB_unit(const float* __restrict__ low,
                                           unsigned short* __restrict__ Bhi,
                                           unsigned short* __restrict__ Blo,
                                           int unit, int tid) {
    int t = unit * 256 + tid;
    int l = t & 63;
    int s = (t >> 6) & 15;
    int u = t >> 10;
    int n = l & 15, quad = l >> 4;
    int p = u * 16 + n;
    int kbase = s * 32 + quad * 8;
    u16x8 vh, vl;
    if (p < PP) {
        int pi = p / WPQ, pj = p % WPQ;
        int base = (kbase >> 4) * HW + pi * WW + pj;   // c fixed across j
#pragma unroll
        for (int j = 0; j < 8; ++j) {
            int kk = kbase + j;
            int di = (kk >> 2) & 3, dj = kk & 3;
            unsigned short h, lo2;
            split_bf16(low[base + di * WW + dj], h, lo2);
            vh[j] = h; vl[j] = lo2;
        }
    } else {
#pragma unroll
        for (int j = 0; j < 8; ++j) { vh[j] = 0; vl[j] = 0; }
    }
    int off = t * 8;
    *reinterpret_cast<u16x8*>(Bhi + off) = vh;
    *reinterpret_cast<u16x8*>(Blo + off) = vl;
}

struct FlagsLds { float part[4][64]; int s_n; int s_q[64]; int s_slot[64]; };

__device__ __forceinline__ void flags_block(const float* __restrict__ low,
                                            const float* __restrict__ high,
                                            const int* __restrict__ mask,
                                            float* __restrict__ invn,
                                            int* __restrict__ excl,
                                            int* __restrict__ qslot,
                                            int* __restrict__ nvalid,
                                            unsigned short* __restrict__ Ahi,
                                            unsigned short* __restrict__ Alo,
                                            FlagsLds& L, int g, int tid) {
    const int pl = tid & 63;
    const int slc = tid >> 6;          // channel slice 0..3
    const int p = g * 64 + pl;
    float s = 0.f;
    if (p < PP) {
        int pi = p / WPQ, pj = p % WPQ;
        int base = pi * WW + pj;
        for (int c = slc * 8; c < slc * 8 + 8; ++c) {
            int b2 = c * HW + base;
#pragma unroll
            for (int di = 0; di < 4; ++di)
#pragma unroll
                for (int dj = 0; dj < 4; ++dj) {
                    float v = low[b2 + di * WW + dj];
                    s += v * v;
                }
        }
    }
    L.part[slc][pl] = s;
    if (tid == 0) L.s_n = 0;
    __syncthreads();
    if (tid < 64 && p < PP) {
        float t4 = L.part[0][tid] + L.part[1][tid] + L.part[2][tid] + L.part[3][tid];
        invn[p] = 1.0f / (sqrtf(t4) + 1e-6f);
        int pi = p / WPQ, pj = p % WPQ;
        int m00 = mask[pi * MSTR + pj];
        int m01 = mask[pi * MSTR + pj + 4];
        int m10 = mask[(pi + 4) * MSTR + pj];
        int m11 = mask[(pi + 4) * MSTR + pj + 4];
        excl[p] = (m00 == 1) ? 1 : 0;
        int slot = -1;
        if (m00 != 0 && m01 != 0 && m10 != 0 && m11 != 0) {
            slot = atomicAdd(nvalid, 1);
            int li = atomicAdd(&L.s_n, 1);
            L.s_q[li] = p;
            L.s_slot[li] = slot;
        }
        qslot[p] = slot;
    }
    __syncthreads();
    // A-pack: 4 queries in flight, 64 chunks (=512 elems) each
    const int nn = L.s_n;
    const int c64 = tid & 63;
    const int ss = c64 >> 2, qd = c64 & 3;
    const int kbase = ss * 32 + qd * 8;
    for (int vi = tid >> 6; vi < nn; vi += 4) {
        int q = L.s_q[vi], slot = L.s_slot[vi];
        int qi = q / WPQ, qj = q % WPQ;
        int base = (kbase >> 4) * HW + qi * WW + qj;
        u16x8 vh, vl;
#pragma unroll
        for (int j = 0; j < 8; ++j) {
            int kk = kbase + j;
            int di = (kk >> 2) & 3, dj = kk & 3;
            unsigned short h, lo2;
            split_bf16(high[base + di * WW + dj], h, lo2);
            vh[j] = h; vl[j] = lo2;
        }
        int u = slot >> 4, m = slot & 15;
        int off = u * 8192 + ss * 512 + (qd * 16 + m) * 8;
        *reinterpret_cast<u16x8*>(Ahi + off) = vh;
        *reinterpret_cast<u16x8*>(Alo + off) = vl;
    }
    // slots in [nv, tile-end): garbage score ROWS only; bestpk[slot>=nv] never read.
}

__device__ __forceinline__ void score_pair(const unsigned short* __restrict__ Ahi,
                                           const unsigned short* __restrict__ Alo,
                                           const unsigned short* __restrict__ Bhi,
                                           const unsigned short* __restrict__ Blo,
                                           const int* __restrict__ excl,
                                           const float* __restrict__ invn,
                                           unsigned long long* __restrict__ bestpk,
                                           int pblk, int qblk, int tid) {
    const int w = tid >> 6;
    const int l = tid & 63;
    const int n = l & 15, quad = l >> 4;
    const int qtile = qblk * 4 + w;
    const int bbase = pblk * 4 * 8192 + l * 8;

    int gpv[4]; bool exv[4]; float ivv[4];
#pragma unroll
    for (int pt = 0; pt < 4; ++pt) {
        gpv[pt] = pblk * 64 + pt * 16 + n;
        if (gpv[pt] < PP) { exv[pt] = (excl[gpv[pt]] != 0); ivv[pt] = invn[gpv[pt]]; }
        else              { exv[pt] = true;                 ivv[pt] = 0.f; }
    }

    f32x4 acc[4];
#pragma unroll
    for (int pt = 0; pt < 4; ++pt) acc[pt] = (f32x4){0.f, 0.f, 0.f, 0.f};

    const int abase = qtile * 8192 + l * 8;
#pragma unroll 4
    for (int s = 0; s < 16; ++s) {
        bf16x8 ah = *reinterpret_cast<const bf16x8*>(Ahi + abase + s * 512);
        bf16x8 al = *reinterpret_cast<const bf16x8*>(Alo + abase + s * 512);
#pragma unroll
        for (int pt = 0; pt < 4; ++pt) {
            bf16x8 bh = *reinterpret_cast<const bf16x8*>(Bhi + bbase + pt * 8192 + s * 512);
            bf16x8 bl = *reinterpret_cast<const bf16x8*>(Blo + bbase + pt * 8192 + s * 512);
            acc[pt] = __builtin_amdgcn_mfma_f32_16x16x32_bf16(ah, bh, acc[pt], 0, 0, 0);
            acc[pt] = __builtin_amdgcn_mfma_f32_16x16x32_bf16(ah, bl, acc[pt], 0, 0, 0);
            acc[pt] = __builtin_amdgcn_mfma_f32_16x16x32_bf16(al, bh, acc[pt], 0, 0, 0);
        }
    }

    // C/D: col n = l&15 (candidate), row m = quad*4 + r (query within qtile)
    float bs[4]; int bi[4];
#pragma unroll
    for (int r = 0; r < 4; ++r) { bs[r] = -3.4e38f; bi[r] = 0x7fffffff; }
#pragma unroll
    for (int pt = 0; pt < 4; ++pt) {
        if (gpv[pt] < PP) {
#pragma unroll
            for (int r = 0; r < 4; ++r) {
                float sv = exv[pt] ? NEGINF : acc[pt][r] * ivv[pt];
                if (sv > bs[r]) { bs[r] = sv; bi[r] = gpv[pt]; }  // pt asc -> lowest gp on tie
            }
        }
    }
#pragma unroll
    for (int off = 1; off <= 8; off <<= 1) {
#pragma unroll
        for (int r = 0; r < 4; ++r) {
            float s2 = __shfl_xor(bs[r], off, 64);
            int   i2 = __shfl_xor(bi[r], off, 64);
            if (s2 > bs[r] || (s2 == bs[r] && i2 < bi[r])) { bs[r] = s2; bi[r] = i2; }
        }
    }
    if (n == 0) {
#pragma unroll
        for (int r = 0; r < 4; ++r) {
            if (bi[r] != 0x7fffffff) {
                unsigned ub = __float_as_uint(bs[r]);
                unsigned mo = (ub & 0x80000000u) ? ~ub : (ub | 0x80000000u);
                unsigned long long pk = ((unsigned long long)mo << 32) | (unsigned)(~bi[r]);
                int slot = qtile * 16 + quad * 4 + r;
                atomicMax(bestpk + slot, pk);
            }
        }
    }
}

struct OutLds { int scnt[64]; int soff[64][17]; };

__device__ __forceinline__ void out_block(const float* __restrict__ low,
                                          const int* __restrict__ qslot,
                                          const unsigned long long* __restrict__ bestpk,
                                          float* __restrict__ out,
                                          OutLds& L, int blk, int tid) {
    const int pixb = blk * 64;
    if (tid < 64) {
        int pix = pixb + tid;
        int i = pix / WW, j = pix % WW;
        int nn = 0;
#pragma unroll
        for (int di = 0; di < 4; ++di) {
            int qi = i - di;
            if (qi < 0 || qi >= HPQ) continue;
#pragma unroll
            for (int dj = 0; dj < 4; ++dj) {
                int qj = j - dj;
                if (qj < 0 || qj >= WPQ) continue;
                int sl = qslot[qi * WPQ + qj];
                if (sl >= 0) {
                    int bb = (int)(~(unsigned)bestpk[sl]);   // low 32 bits = ~best_idx
                    L.soff[tid][nn++] = (bb / WPQ + di) * WW + (bb % WPQ + dj);
                }
            }
        }
        L.scnt[tid] = nn;
    }
    __syncthreads();
    const int pl = tid & 63, cg2 = tid >> 6;
    const int nn = L.scnt[pl];
    const int pix = pixb + pl;
    const float inv = 1.0f / ((float)nn + 1e-6f);
#pragma unroll
    for (int k = 0; k < 8; ++k) {
        int c = cg2 * 8 + k;
        int base = c * HW;
        float a;
        if (nn > 0) {
            a = 0.f;
            for (int t2 = 0; t2 < nn; ++t2) a += low[base + L.soff[pl][t2]];
            a *= inv;
        } else {
            a = low[base + pix];
        }
        out[base + pix] = a;
    }
}

// ================= kernels =================

__global__ __launch_bounds__(256) void k_main(const float* __restrict__ low,
                                              const float* __restrict__ high,
                                              const int* __restrict__ mask,
                                              float* __restrict__ invn,
                                              int* __restrict__ excl,
                                              int* __restrict__ qslot,
                                              int* __restrict__ nvalid,
                                              unsigned short* __restrict__ Bhi,
                                              unsigned short* __restrict__ Blo,
                                              unsigned short* __restrict__ Ahi,
                                              unsigned short* __restrict__ Alo) {
    const int g = blockIdx.x;
    if (g >= NTILE) {
        packB_unit(low, Bhi, Blo, g - NTILE, threadIdx.x);
        return;
    }
    __shared__ FlagsLds L;
    flags_block(low, high, mask, invn, excl, qslot, nvalid, Ahi, Alo, L, g, threadIdx.x);
}

// XCD-aware swizzled score grid: 1152 blocks.
//   xcd  = bid % 8   (blockIdx round-robins across the 8 XCDs)
//   slot = bid / 8   in [0,144):  pblk = xcd*12 + slot%12  (skip >=93),
//                                 qblk = slot/12, stride 12.
// Coverage: slot = qb*12 + pl is a bijection onto (pl 0..11, qb 0..11), so every
// (pblk, qblk) pair is computed exactly once for any nv <= 5929.
// Effect: all jobs sharing a pblk (same 128 KB B-tile) run on ONE XCD; per-XCD
// working set = 12 pblks * 128 KB (B) + nqblk * 128 KB (A) ~ 2.3 MB -> fits 4 MB L2.
__global__ __launch_bounds__(256) void k_score(const unsigned short* __restrict__ Ahi,
                                               const unsigned short* __restrict__ Alo,
                                               const unsigned short* __restrict__ Bhi,
                                               const unsigned short* __restrict__ Blo,
                                               const int* __restrict__ excl,
                                               const float* __restrict__ invn,
                                               const int* __restrict__ nvalid,
                                               unsigned long long* __restrict__ bestpk) {
    const int nv = *nvalid;
    const int nqblk = (nv + 63) >> 6;
    const int xcd = blockIdx.x & 7;
    const int slot = blockIdx.x >> 3;        // 0..143
    const int pblk = xcd * 12 + (slot % 12);
    if (pblk >= NTILE) return;
    for (int qblk = slot / 12; qblk < nqblk; qblk += 12)
        score_pair(Ahi, Alo, Bhi, Blo, excl, invn, bestpk, pblk, qblk, threadIdx.x);
}

__global__ __launch_bounds__(256) void k_out(const float* __restrict__ low,
                                             const int* __restrict__ qslot,
                                             const unsigned long long* __restrict__ bestpk,
                                             float* __restrict__ out) {
    __shared__ OutLds L;
    out_block(low, qslot, bestpk, out, L, blockIdx.x, threadIdx.x);
}

extern "C" void kernel_launch(void* const* d_in, const int* in_sizes, int n_in,
                              void* d_out, int out_size, void* d_ws, size_t ws_size,
                              hipStream_t stream) {
    const float* low  = (const float*)d_in[0];
    const float* high = (const float*)d_in[1];
    const int*   mask = (const int*)d_in[2];
    float* out = (float*)d_out;

    char* ws = (char*)d_ws;
    int* nvalid = (int*)ws;                                       // 64 B
    unsigned long long* bestpk = (unsigned long long*)(ws + 64);  // 6144*8 = 49152 -> 49216
    int*   qslot = (int*)(ws + 49216);                            // 23808 -> 73024
    float* invn  = (float*)(ws + 73024);                          // 23808 -> 96832
    int*   excl  = (int*)(ws + 96832);                            // 23808 -> 120640
    unsigned short* Ahi = (unsigned short*)(ws + 120640);         // 372 tiles: 6,094,848
    unsigned short* Alo = (unsigned short*)(ws + 6215488);        // 6,094,848
    unsigned short* Bhi = (unsigned short*)(ws + 12310336);       // 6,094,848
    unsigned short* Blo = (unsigned short*)(ws + 18405184);       // end 24,500,032 (~24.5 MB)

    hipMemsetAsync(ws, 0, 49216, stream);   // nvalid + bestpk
    hipLaunchKernelGGL(k_main, dim3(NTILE + QTILES * 4), dim3(256), 0, stream,
                       low, high, mask, invn, excl, qslot, nvalid, Bhi, Blo, Ahi, Alo);
    hipLaunchKernelGGL(k_score, dim3(1152), dim3(256), 0, stream,
                       Ahi, Alo, Bhi, Blo, excl, invn, nvalid, bestpk);
    hipLaunchKernelGGL(k_out, dim3(100), dim3(256), 0, stream,
                       low, qslot, bestpk, out);
}

// Round 8
// 113.619 us; speedup vs baseline: 2.6088x; 1.0101x over previous
//
#include <hip/hip_runtime.h>
#include <hip/hip_bf16.h>

#define CC    32
#define HH    80
#define WW    80
#define HW    6400     // 80*80
#define HPQ   77
#define WPQ   77
#define PP    5929     // 77*77
#define MSTR  81
#define NTILE 93       // 93 candidate blocks of 64
#define QTILES 372     // 5952/16 tiles
#define NEGINF (-1e9f)

typedef __attribute__((ext_vector_type(4))) float f32x4;
typedef __attribute__((ext_vector_type(4), aligned(4))) float f32x4u;   // 4B-aligned vector load
typedef __attribute__((ext_vector_type(8))) short bf16x8;
typedef __attribute__((ext_vector_type(8))) unsigned short u16x8;

__device__ __forceinline__ void split_bf16(float v, unsigned short& hi, unsigned short& lo) {
    __hip_bfloat16 h = __float2bfloat16(v);
    float hf = __bfloat162float(h);
    __hip_bfloat16 lw = __float2bfloat16(v - hf);
    hi = *reinterpret_cast<unsigned short*>(&h);
    lo = *reinterpret_cast<unsigned short*>(&lw);
}

// ---- device helpers (same math as the R3/R6 chain that passed absmax 0.0) ----

// pack 8 elems = two rows of 4 consecutive floats -> two dwordx4 loads.
// kbase = s*32 + quad*8: (kbase>>2)&3 = di0 in {0,2}, elems j0-3 row di0, j4-7 row di0+1.
__device__ __forceinline__ void packB_unit(const float* __restrict__ low,
                                           unsigned short* __restrict__ Bhi,
                                           unsigned short* __restrict__ Blo,
                                           int unit, int tid) {
    int t = unit * 256 + tid;
    int l = t & 63;
    int s = (t >> 6) & 15;
    int u = t >> 10;
    int n = l & 15, quad = l >> 4;
    int p = u * 16 + n;
    int kbase = s * 32 + quad * 8;
    u16x8 vh, vl;
    if (p < PP) {
        int pi = p / WPQ, pj = p % WPQ;
        int di0 = (kbase >> 2) & 3;
        const float* rp = low + (kbase >> 4) * HW + (pi + di0) * WW + pj;
        f32x4u v0 = *reinterpret_cast<const f32x4u*>(rp);
        f32x4u v1 = *reinterpret_cast<const f32x4u*>(rp + WW);
#pragma unroll
        for (int j = 0; j < 4; ++j) {
            unsigned short h, lo2;
            split_bf16(v0[j], h, lo2);
            vh[j] = h; vl[j] = lo2;
            split_bf16(v1[j], h, lo2);
            vh[j + 4] = h; vl[j + 4] = lo2;
        }
    } else {
#pragma unroll
        for (int j = 0; j < 8; ++j) { vh[j] = 0; vl[j] = 0; }
    }
    int off = t * 8;
    *reinterpret_cast<u16x8*>(Bhi + off) = vh;
    *reinterpret_cast<u16x8*>(Blo + off) = vl;
}

struct FlagsLds { float part[4][64]; int s_n; int s_q[64]; int s_slot[64]; };

__device__ __forceinline__ void flags_block(const float* __restrict__ low,
                                            const float* __restrict__ high,
                                            const int* __restrict__ mask,
                                            float* __restrict__ invn,
                                            int* __restrict__ excl,
                                            int* __restrict__ qslot,
                                            int* __restrict__ nvalid,
                                            unsigned short* __restrict__ Ahi,
                                            unsigned short* __restrict__ Alo,
                                            FlagsLds& L, int g, int tid) {
    const int pl = tid & 63;
    const int slc = tid >> 6;          // channel slice 0..3
    const int p = g * 64 + pl;
    float s = 0.f;
    if (p < PP) {
        int pi = p / WPQ, pj = p % WPQ;
        int base = pi * WW + pj;
        for (int c = slc * 8; c < slc * 8 + 8; ++c) {
            const float* bp = low + c * HW + base;
#pragma unroll
            for (int di = 0; di < 4; ++di) {
                f32x4u v = *reinterpret_cast<const f32x4u*>(bp + di * WW);
#pragma unroll
                for (int dj = 0; dj < 4; ++dj) s += v[dj] * v[dj];
            }
        }
    }
    L.part[slc][pl] = s;
    if (tid == 0) L.s_n = 0;
    __syncthreads();
    if (tid < 64 && p < PP) {
        float t4 = L.part[0][tid] + L.part[1][tid] + L.part[2][tid] + L.part[3][tid];
        invn[p] = 1.0f / (sqrtf(t4) + 1e-6f);
        int pi = p / WPQ, pj = p % WPQ;
        int m00 = mask[pi * MSTR + pj];
        int m01 = mask[pi * MSTR + pj + 4];
        int m10 = mask[(pi + 4) * MSTR + pj];
        int m11 = mask[(pi + 4) * MSTR + pj + 4];
        excl[p] = (m00 == 1) ? 1 : 0;
        int slot = -1;
        if (m00 != 0 && m01 != 0 && m10 != 0 && m11 != 0) {
            slot = atomicAdd(nvalid, 1);
            int li = atomicAdd(&L.s_n, 1);
            L.s_q[li] = p;
            L.s_slot[li] = slot;
        }
        qslot[p] = slot;
    }
    __syncthreads();
    // A-pack: 4 queries in flight, 64 chunks (=512 elems) each; two dwordx4 per chunk
    const int nn = L.s_n;
    const int c64 = tid & 63;
    const int ss = c64 >> 2, qd = c64 & 3;
    const int kbase = ss * 32 + qd * 8;
    const int di0 = (kbase >> 2) & 3;
    for (int vi = tid >> 6; vi < nn; vi += 4) {
        int q = L.s_q[vi], slot = L.s_slot[vi];
        int qi = q / WPQ, qj = q % WPQ;
        const float* rp = high + (kbase >> 4) * HW + (qi + di0) * WW + qj;
        f32x4u v0 = *reinterpret_cast<const f32x4u*>(rp);
        f32x4u v1 = *reinterpret_cast<const f32x4u*>(rp + WW);
        u16x8 vh, vl;
#pragma unroll
        for (int j = 0; j < 4; ++j) {
            unsigned short h, lo2;
            split_bf16(v0[j], h, lo2);
            vh[j] = h; vl[j] = lo2;
            split_bf16(v1[j], h, lo2);
            vh[j + 4] = h; vl[j + 4] = lo2;
        }
        int u = slot >> 4, m = slot & 15;
        int off = u * 8192 + ss * 512 + (qd * 16 + m) * 8;
        *reinterpret_cast<u16x8*>(Ahi + off) = vh;
        *reinterpret_cast<u16x8*>(Alo + off) = vl;
    }
    // slots in [nv, tile-end): garbage score ROWS only; bestpk[slot>=nv] never read.
}

__device__ __forceinline__ void score_pair(const unsigned short* __restrict__ Ahi,
                                           const unsigned short* __restrict__ Alo,
                                           const unsigned short* __restrict__ Bhi,
                                           const unsigned short* __restrict__ Blo,
                                           const int* __restrict__ excl,
                                           const float* __restrict__ invn,
                                           unsigned long long* __restrict__ bestpk,
                                           int pblk, int qblk, int tid) {
    const int w = tid >> 6;
    const int l = tid & 63;
    const int n = l & 15, quad = l >> 4;
    const int qtile = qblk * 4 + w;
    const int bbase = pblk * 4 * 8192 + l * 8;

    int gpv[4]; bool exv[4]; float ivv[4];
#pragma unroll
    for (int pt = 0; pt < 4; ++pt) {
        gpv[pt] = pblk * 64 + pt * 16 + n;
        if (gpv[pt] < PP) { exv[pt] = (excl[gpv[pt]] != 0); ivv[pt] = invn[gpv[pt]]; }
        else              { exv[pt] = true;                 ivv[pt] = 0.f; }
    }

    f32x4 acc[4];
#pragma unroll
    for (int pt = 0; pt < 4; ++pt) acc[pt] = (f32x4){0.f, 0.f, 0.f, 0.f};

    const int abase = qtile * 8192 + l * 8;
#pragma unroll 4
    for (int s = 0; s < 16; ++s) {
        bf16x8 ah = *reinterpret_cast<const bf16x8*>(Ahi + abase + s * 512);
        bf16x8 al = *reinterpret_cast<const bf16x8*>(Alo + abase + s * 512);
#pragma unroll
        for (int pt = 0; pt < 4; ++pt) {
            bf16x8 bh = *reinterpret_cast<const bf16x8*>(Bhi + bbase + pt * 8192 + s * 512);
            bf16x8 bl = *reinterpret_cast<const bf16x8*>(Blo + bbase + pt * 8192 + s * 512);
            acc[pt] = __builtin_amdgcn_mfma_f32_16x16x32_bf16(ah, bh, acc[pt], 0, 0, 0);
            acc[pt] = __builtin_amdgcn_mfma_f32_16x16x32_bf16(ah, bl, acc[pt], 0, 0, 0);
            acc[pt] = __builtin_amdgcn_mfma_f32_16x16x32_bf16(al, bh, acc[pt], 0, 0, 0);
        }
    }

    // C/D: col n = l&15 (candidate), row m = quad*4 + r (query within qtile)
    float bs[4]; int bi[4];
#pragma unroll
    for (int r = 0; r < 4; ++r) { bs[r] = -3.4e38f; bi[r] = 0x7fffffff; }
#pragma unroll
    for (int pt = 0; pt < 4; ++pt) {
        if (gpv[pt] < PP) {
#pragma unroll
            for (int r = 0; r < 4; ++r) {
                float sv = exv[pt] ? NEGINF : acc[pt][r] * ivv[pt];
                if (sv > bs[r]) { bs[r] = sv; bi[r] = gpv[pt]; }  // pt asc -> lowest gp on tie
            }
        }
    }
#pragma unroll
    for (int off = 1; off <= 8; off <<= 1) {
#pragma unroll
        for (int r = 0; r < 4; ++r) {
            float s2 = __shfl_xor(bs[r], off, 64);
            int   i2 = __shfl_xor(bi[r], off, 64);
            if (s2 > bs[r] || (s2 == bs[r] && i2 < bi[r])) { bs[r] = s2; bi[r] = i2; }
        }
    }
    if (n == 0) {
#pragma unroll
        for (int r = 0; r < 4; ++r) {
            if (bi[r] != 0x7fffffff) {
                unsigned ub = __float_as_uint(bs[r]);
                unsigned mo = (ub & 0x80000000u) ? ~ub : (ub | 0x80000000u);
                unsigned long long pk = ((unsigned long long)mo << 32) | (unsigned)(~bi[r]);
                int slot = qtile * 16 + quad * 4 + r;
                atomicMax(bestpk + slot, pk);
            }
        }
    }
}

struct OutLds { int scnt[64]; int soff[64][17]; };

__device__ __forceinline__ void out_block(const float* __restrict__ low,
                                          const int* __restrict__ qslot,
                                          const unsigned long long* __restrict__ bestpk,
                                          float* __restrict__ out,
                                          OutLds& L, int blk, int tid) {
    const int pixb = blk * 64;
    if (tid < 64) {
        int pix = pixb + tid;
        int i = pix / WW, j = pix % WW;
        int nn = 0;
#pragma unroll
        for (int di = 0; di < 4; ++di) {
            int qi = i - di;
            if (qi < 0 || qi >= HPQ) continue;
#pragma unroll
            for (int dj = 0; dj < 4; ++dj) {
                int qj = j - dj;
                if (qj < 0 || qj >= WPQ) continue;
                int sl = qslot[qi * WPQ + qj];
                if (sl >= 0) {
                    int bb = (int)(~(unsigned)bestpk[sl]);   // low 32 bits = ~best_idx
                    L.soff[tid][nn++] = (bb / WPQ + di) * WW + (bb % WPQ + dj);
                }
            }
        }
        L.scnt[tid] = nn;
    }
    __syncthreads();
    const int pl = tid & 63, cg2 = tid >> 6;
    const int nn = L.scnt[pl];
    const int pix = pixb + pl;
    const float inv = 1.0f / ((float)nn + 1e-6f);
#pragma unroll
    for (int k = 0; k < 8; ++k) {
        int c = cg2 * 8 + k;
        int base = c * HW;
        float a;
        if (nn > 0) {
            a = 0.f;
            for (int t2 = 0; t2 < nn; ++t2) a += low[base + L.soff[pl][t2]];
            a *= inv;
        } else {
            a = low[base + pix];
        }
        out[base + pix] = a;
    }
}

// ================= kernels =================

__global__ __launch_bounds__(256) void k_main(const float* __restrict__ low,
                                              const float* __restrict__ high,
                                              const int* __restrict__ mask,
                                              float* __restrict__ invn,
                                              int* __restrict__ excl,
                                              int* __restrict__ qslot,
                                              int* __restrict__ nvalid,
                                              unsigned short* __restrict__ Bhi,
                                              unsigned short* __restrict__ Blo,
                                              unsigned short* __restrict__ Ahi,
                                              unsigned short* __restrict__ Alo,
                                              unsigned long long* __restrict__ bestpk) {
    const int g = blockIdx.x;
    if (g >= NTILE) {
        const int unit = g - NTILE;
        if (unit < 24) {                       // fold bestpk zeroing into B-pack blocks
            int e = unit * 256 + threadIdx.x;  // 24*256 = 6144 entries
            bestpk[e] = 0ull;
        }
        packB_unit(low, Bhi, Blo, unit, threadIdx.x);
        return;
    }
    __shared__ FlagsLds L;
    flags_block(low, high, mask, invn, excl, qslot, nvalid, Ahi, Alo, L, g, threadIdx.x);
}

// XCD-aware swizzled score grid: 1152 blocks.
//   xcd  = bid % 8, slot = bid / 8 in [0,144): pblk = xcd*12 + slot%12 (skip >=93),
//   qblk = slot/12, stride 12. slot = qb*12 + pl is a bijection -> every (pblk,qblk)
//   pair computed exactly once for any nv <= 5929. Same-pblk jobs pinned to one XCD;
//   per-XCD working set ~ 12*128KB (B) + nqblk*128KB (A) ~ 2.3 MB -> fits 4 MB L2.
__global__ __launch_bounds__(256) void k_score(const unsigned short* __restrict__ Ahi,
                                               const unsigned short* __restrict__ Alo,
                                               const unsigned short* __restrict__ Bhi,
                                               const unsigned short* __restrict__ Blo,
                                               const int* __restrict__ excl,
                                               const float* __restrict__ invn,
                                               const int* __restrict__ nvalid,
                                               unsigned long long* __restrict__ bestpk) {
    const int nv = *nvalid;
    const int nqblk = (nv + 63) >> 6;
    const int xcd = blockIdx.x & 7;
    const int slot = blockIdx.x >> 3;        // 0..143
    const int pblk = xcd * 12 + (slot % 12);
    if (pblk >= NTILE) return;
    for (int qblk = slot / 12; qblk < nqblk; qblk += 12)
        score_pair(Ahi, Alo, Bhi, Blo, excl, invn, bestpk, pblk, qblk, threadIdx.x);
}

__global__ __launch_bounds__(256) void k_out(const float* __restrict__ low,
                                             const int* __restrict__ qslot,
                                             const unsigned long long* __restrict__ bestpk,
                                             float* __restrict__ out) {
    __shared__ OutLds L;
    out_block(low, qslot, bestpk, out, L, blockIdx.x, threadIdx.x);
}

extern "C" void kernel_launch(void* const* d_in, const int* in_sizes, int n_in,
                              void* d_out, int out_size, void* d_ws, size_t ws_size,
                              hipStream_t stream) {
    const float* low  = (const float*)d_in[0];
    const float* high = (const float*)d_in[1];
    const int*   mask = (const int*)d_in[2];
    float* out = (float*)d_out;

    char* ws = (char*)d_ws;
    int* nvalid = (int*)ws;                                       // 64 B
    unsigned long long* bestpk = (unsigned long long*)(ws + 64);  // 6144*8 = 49152 -> 49216
    int*   qslot = (int*)(ws + 49216);                            // 23808 -> 73024
    float* invn  = (float*)(ws + 73024);                          // 23808 -> 96832
    int*   excl  = (int*)(ws + 96832);                            // 23808 -> 120640
    unsigned short* Ahi = (unsigned short*)(ws + 120640);         // 372 tiles: 6,094,848
    unsigned short* Alo = (unsigned short*)(ws + 6215488);        // 6,094,848
    unsigned short* Bhi = (unsigned short*)(ws + 12310336);       // 6,094,848
    unsigned short* Blo = (unsigned short*)(ws + 18405184);       // end 24,500,032 (~24.5 MB)

    hipMemsetAsync(nvalid, 0, 64, stream);   // nvalid only; bestpk zeroed in k_main
    hipLaunchKernelGGL(k_main, dim3(NTILE + QTILES * 4), dim3(256), 0, stream,
                       low, high, mask, invn, excl, qslot, nvalid, Bhi, Blo, Ahi, Alo, bestpk);
    hipLaunchKernelGGL(k_score, dim3(1152), dim3(256), 0, stream,
                       Ahi, Alo, Bhi, Blo, excl, invn, nvalid, bestpk);
    hipLaunchKernelGGL(k_out, dim3(100), dim3(256), 0, stream,
                       low, qslot, bestpk, out);
}